// Round 11
// baseline (192.177 us; speedup 1.0000x reference)
//
#include <hip/hip_runtime.h>
#include <hip/hip_bf16.h>
#include <math.h>

#define N_NODES 20000
#define MPAD 20096               // 157*128
#define N_EDGES 320000
#define EP (N_EDGES + N_NODES)   // 340000
#define F_IN 256
#define NHID 64
#define H1 8
#define D1 512
#define NCLS 40
#define NEG_SLOPE 0.2f
#define MAXD 128

typedef __attribute__((ext_vector_type(8))) short bf16x8;
typedef __attribute__((ext_vector_type(4))) float f32x4;

__device__ __forceinline__ float wave_max(float v) {
#pragma unroll
  for (int o = 32; o > 0; o >>= 1) v = fmaxf(v, __shfl_xor(v, o));
  return v;
}
__device__ __forceinline__ float wave_sum(float v) {
#pragma unroll
  for (int o = 32; o > 0; o >>= 1) v += __shfl_xor(v, o);
  return v;
}
__device__ __forceinline__ float bf2f(unsigned short u) {
  union { unsigned int i; float f; } c; c.i = ((unsigned int)u) << 16; return c.f;
}
__device__ __forceinline__ unsigned short f2bf(float f) {
  union { float f; unsigned int i; } c; c.f = f;
  unsigned int x = c.i;
  return (unsigned short)((x + 0x7fffu + ((x >> 16) & 1u)) >> 16);  // RNE
}
__device__ __forceinline__ float asf(unsigned int u) {
  union { unsigned int i; float f; } c; c.i = u; return c.f;
}
__device__ __forceinline__ float lrelu(float x) { return x > 0.f ? x : NEG_SLOPE * x; }

__device__ __forceinline__ void gload16(const void* g, void* l) {
  __builtin_amdgcn_global_load_lds((const __attribute__((address_space(1))) void*)g,
                                   (__attribute__((address_space(3))) void*)l, 16, 0, 0);
}

// ---------------- fused prep ----------------
#define PB_CONV 2512             // MPAD*F_IN/8/256
#define PB_TW1  (PB_CONV + 32)
#define PB_TW2  (PB_TW1 + 96)
#define PB_ZERO (PB_TW2 + 157)
#define PB_PAD  (PB_ZERO + 24)
__global__ __launch_bounds__(256) void prep_kernel(const float* __restrict__ x,
                                                   const float* __restrict__ W1,
                                                   const float* __restrict__ W2,
                                                   unsigned short* __restrict__ xb,
                                                   unsigned short* __restrict__ wb1t,
                                                   unsigned short* __restrict__ wb2t,
                                                   int* __restrict__ deg,
                                                   int* __restrict__ cursor,
                                                   unsigned short* __restrict__ out1b) {
  __shared__ float tsh[64][65];
  int bid = blockIdx.x;
  int t = threadIdx.x;
  if (bid < PB_CONV) {
    size_t base = ((size_t)bid * 256 + t) * 8;
    int row = (int)(base >> 8);
    ushort4 o0, o1;
    if (row < N_NODES) {
      float4 v0 = *(const float4*)&x[base];
      float4 v1 = *(const float4*)&x[base + 4];
      o0 = make_ushort4(f2bf(v0.x), f2bf(v0.y), f2bf(v0.z), f2bf(v0.w));
      o1 = make_ushort4(f2bf(v1.x), f2bf(v1.y), f2bf(v1.z), f2bf(v1.w));
    } else {
      o0 = make_ushort4(0, 0, 0, 0); o1 = o0;
    }
    *(ushort4*)&xb[base] = o0;
    *(ushort4*)&xb[base + 4] = o1;
  } else if (bid < PB_TW1) {
    int b2 = bid - PB_CONV;
    int bk = b2 & 3, bn = b2 >> 2;
    int tr = t >> 4, tc4 = (t & 15) * 4;
#pragma unroll
    for (int i = 0; i < 4; ++i) {
      int k = i * 16 + tr;
      float4 v = *(const float4*)&W1[(size_t)(bk * 64 + k) * D1 + bn * 64 + tc4];
      tsh[k][tc4] = v.x; tsh[k][tc4 + 1] = v.y; tsh[k][tc4 + 2] = v.z; tsh[k][tc4 + 3] = v.w;
    }
    __syncthreads();
#pragma unroll
    for (int i = 0; i < 4; ++i) {
      int n = i * 16 + tr;
      ushort4 o = make_ushort4(f2bf(tsh[tc4][n]), f2bf(tsh[tc4 + 1][n]),
                               f2bf(tsh[tc4 + 2][n]), f2bf(tsh[tc4 + 3][n]));
      *(ushort4*)&wb1t[(size_t)(bn * 64 + n) * F_IN + bk * 64 + tc4] = o;
    }
  } else if (bid < PB_TW2) {
    int idx = (bid - PB_TW1) * 256 + t;
    int c = idx >> 9, k = idx & 511;
    wb2t[idx] = f2bf((c < NCLS) ? W2[(size_t)k * NCLS + c] : 0.f);
  } else if (bid < PB_ZERO) {
    int idx = (bid - PB_TW2) * 256 + t;
    if (idx < N_NODES) deg[idx] = 0;
    else if (idx < 2 * N_NODES) cursor[idx - N_NODES] = 0;
  } else {
    int idx = (bid - PB_ZERO) * 256 + t;
    uint4 z = make_uint4(0, 0, 0, 0);
    *(uint4*)((char*)out1b + (size_t)N_NODES * D1 * 2 + (size_t)idx * 16) = z;
  }
}

// ---------------- CSR build ----------------
__global__ void count_deg(const int* __restrict__ ei, int* __restrict__ deg) {
  int e = blockIdx.x * blockDim.x + threadIdx.x;
  if (e >= EP) return;
  int dst = (e < N_EDGES) ? ei[N_EDGES + e] : (e - N_EDGES);
  atomicAdd(&deg[dst], 1);
}

#define SCAN_T 1024
#define SCAN_CHUNK 20
__global__ __launch_bounds__(1024) void scan_kernel(const int* __restrict__ deg,
                                                    int* __restrict__ offsets) {
  __shared__ int wsum[16];
  int t = threadIdx.x;
  int w = t >> 6, lane = t & 63;
  int lo = t * SCAN_CHUNK;
  int hi = min(lo + SCAN_CHUNK, N_NODES);
  int s = 0;
  for (int i = lo; i < hi; ++i) s += deg[i];
  int incl = s;
#pragma unroll
  for (int o = 1; o < 64; o <<= 1) {
    int v = __shfl_up(incl, o);
    if (lane >= o) incl += v;
  }
  if (lane == 63) wsum[w] = incl;
  __syncthreads();
  if (t == 0) {
    int run = 0;
#pragma unroll
    for (int i = 0; i < 16; ++i) { int v = wsum[i]; wsum[i] = run; run += v; }
  }
  __syncthreads();
  int off = wsum[w] + incl - s;
  for (int i = lo; i < hi; ++i) { offsets[i] = off; off += deg[i]; }
  if (hi == N_NODES && lo < N_NODES) offsets[N_NODES] = off;
}

__global__ void scatter_edges(const int* __restrict__ ei, const int* __restrict__ offsets,
                              int* __restrict__ cursor, int* __restrict__ edge_src) {
  int e = blockIdx.x * blockDim.x + threadIdx.x;
  if (e >= EP) return;
  int src, dst;
  if (e < N_EDGES) { src = ei[e]; dst = ei[N_EDGES + e]; }
  else             { src = dst = e - N_EDGES; }
  int pos = offsets[dst] + atomicAdd(&cursor[dst], 1);
  edge_src[pos] = src;
}

// ---------------- GEMM1 (MFMA): h1b = xb @ W1, fused alpha1. BK=64 ----------------
__global__ __launch_bounds__(256) void gemm1_mfma(const unsigned short* __restrict__ xb,
                                                  const unsigned short* __restrict__ wb1t,
                                                  const float* __restrict__ a_src,
                                                  const float* __restrict__ a_dst,
                                                  unsigned short* __restrict__ h1b,
                                                  float* __restrict__ asrc,
                                                  float* __restrict__ adst) {
  __shared__ unsigned short As[128 * 64];
  __shared__ unsigned short Bs[128 * 64];
  int tid = threadIdx.x;
  int w = tid >> 6, lane = tid & 63;
  int bn = blockIdx.x & 3, bm = blockIdx.x >> 2;
  int row0 = bm * 128, col0 = bn * 128;
  int wr = w >> 1, wc = w & 1;
  int cl = lane & 15, hi = lane >> 4;
  f32x4 acc[4][4] = {};
  for (int k0 = 0; k0 < F_IN; k0 += 64) {
#pragma unroll
    for (int c = 0; c < 4; ++c) {
      int slot = c * 256 + tid;
      int r = slot >> 3;
      int q = (slot & 7) ^ (r & 7);
      gload16(xb + (size_t)(row0 + r) * F_IN + k0 + q * 8, (char*)As + (c * 256 + w * 64) * 16);
      gload16(wb1t + (size_t)(col0 + r) * F_IN + k0 + q * 8, (char*)Bs + (c * 256 + w * 64) * 16);
    }
    __syncthreads();
#pragma unroll
    for (int kk = 0; kk < 2; ++kk) {
      bf16x8 a[4], b[4];
#pragma unroll
      for (int m = 0; m < 4; ++m) {
        int r = wr * 64 + m * 16 + cl;
        a[m] = *(const bf16x8*)&As[r * 64 + ((((kk * 4 + hi)) ^ (r & 7)) << 3)];
      }
#pragma unroll
      for (int n = 0; n < 4; ++n) {
        int r = wc * 64 + n * 16 + cl;
        b[n] = *(const bf16x8*)&Bs[r * 64 + ((((kk * 4 + hi)) ^ (r & 7)) << 3)];
      }
#pragma unroll
      for (int m = 0; m < 4; ++m)
#pragma unroll
        for (int n = 0; n < 4; ++n)
          acc[m][n] = __builtin_amdgcn_mfma_f32_16x16x32_bf16(a[m], b[n], acc[m][n], 0, 0, 0);
    }
    __syncthreads();
  }
  int head = bn * 2 + wc;
  float asv[4], adv[4];
#pragma unroll
  for (int n = 0; n < 4; ++n) {
    asv[n] = a_src[head * 64 + n * 16 + cl];
    adv[n] = a_dst[head * 64 + n * 16 + cl];
  }
#pragma unroll
  for (int m = 0; m < 4; ++m) {
#pragma unroll
    for (int r = 0; r < 4; ++r) {
      int grow = row0 + wr * 64 + m * 16 + hi * 4 + r;
      float ps = acc[m][0][r] * asv[0] + acc[m][1][r] * asv[1] +
                 acc[m][2][r] * asv[2] + acc[m][3][r] * asv[3];
      float pd = acc[m][0][r] * adv[0] + acc[m][1][r] * adv[1] +
                 acc[m][2][r] * adv[2] + acc[m][3][r] * adv[3];
#pragma unroll
      for (int o = 8; o > 0; o >>= 1) { ps += __shfl_xor(ps, o); pd += __shfl_xor(pd, o); }
      if (grow < N_NODES) {
#pragma unroll
        for (int n = 0; n < 4; ++n)
          h1b[(size_t)grow * D1 + col0 + wc * 64 + n * 16 + cl] = f2bf(acc[m][n][r]);
        if (cl == 0) { asrc[grow * H1 + head] = ps; adst[grow * H1 + head] = pd; }
      }
    }
  }
}

// ---------------- agg1: head-sliced, XCD-affine. block = 4 waves, each (node, head). ----------------
// bid = ng*8 + head -> under round-robin block->XCD mapping each XCD touches only one head's
// 128B slice of h1b (2.56MB < 4MB per-XCD L2). No LDS, no barriers.
// NOTE: all __shfl sources must be ACTIVE lanes (ds_bpermute returns undefined from inactive
// lanes) -> shfl is done in uniform control flow, invalid slots neutralized by a=0.
__global__ __launch_bounds__(256) void agg1_kernel(const int* __restrict__ offsets,
                                                   const int* __restrict__ edge_src,
                                                   const float* __restrict__ asrc,
                                                   const float* __restrict__ adst,
                                                   const unsigned short* __restrict__ h1b,
                                                   const float* __restrict__ b1,
                                                   unsigned short* __restrict__ out1b) {
  int w = threadIdx.x >> 6, lane = threadIdx.x & 63;
  int bid = blockIdx.x;
  int head = bid & 7;
  int n = (bid >> 3) * 4 + w;
  int base = offsets[n];
  int deg = offsets[n + 1] - base;

  // softmax: edge == lane (deg <= 64 fast path)
  float adv = adst[n * H1 + head];
  int src = 0;
  float ev = -INFINITY;
  if (lane < deg) {
    src = edge_src[base + lane];
    ev = lrelu(asrc[src * H1 + head] + adv);
  }
  float mx = -INFINITY;
  for (int e = 64 + lane; e < deg; e += 64)   // guard, never runs for this graph
    mx = fmaxf(mx, lrelu(asrc[edge_src[base + e] * H1 + head] + adv));
  float m = wave_max(fmaxf(ev, mx));
  float ssl = (lane < deg) ? __expf(ev - m) : 0.f;
  for (int e = 64 + lane; e < deg; e += 64)   // guard
    ssl += __expf(lrelu(asrc[edge_src[base + e] * H1 + head] + adv) - m);
  float inv = 1.f / (wave_sum(ssl) + 1e-16f);
  float alpha = (lane < deg) ? __expf(ev - m) * inv : 0.f;
  int rowoff = src << 10;                     // byte offset of src row in h1b

  // gather: 4 edges per iteration; 16 lanes x 8B (4 bf16 ch) per edge.
  // Branch-free: shfl executed by all 64 lanes (sources active); invalid slot -> a = 0,
  // address clamped to edge 0's row (always valid, deg >= 1).
  int eg = lane >> 4, cl = lane & 15;
  const char* hb = (const char*)h1b + head * 128 + cl * 8;
  float a0 = 0.f, a1 = 0.f, a2 = 0.f, a3 = 0.f;
  int dc = min(deg, 64);
  for (int e0 = 0; e0 < dc; e0 += 4) {
    int e = e0 + eg;
    int esafe = (e < dc) ? e : 0;
    float a = __shfl(alpha, esafe);
    int ro = __shfl(rowoff, esafe);
    if (e >= dc) a = 0.f;
    uint2 uv = *(const uint2*)(hb + ro);
    a0 += a * asf(uv.x << 16);
    a1 += a * asf(uv.x & 0xffff0000u);
    a2 += a * asf(uv.y << 16);
    a3 += a * asf(uv.y & 0xffff0000u);
  }
  for (int e = 64 + eg; e < deg; e += 4) {    // guard, never runs for this graph
    int s2 = edge_src[base + e];
    float a = __expf(lrelu(asrc[s2 * H1 + head] + adv) - m) * inv;
    uint2 uv = *(const uint2*)(hb + ((size_t)s2 << 10));
    a0 += a * asf(uv.x << 16);
    a1 += a * asf(uv.x & 0xffff0000u);
    a2 += a * asf(uv.y << 16);
    a3 += a * asf(uv.y & 0xffff0000u);
  }
  // reduce across the 4 edge groups (lanes cl, cl+16, cl+32, cl+48)
  a0 += __shfl_xor(a0, 16); a0 += __shfl_xor(a0, 32);
  a1 += __shfl_xor(a1, 16); a1 += __shfl_xor(a1, 32);
  a2 += __shfl_xor(a2, 16); a2 += __shfl_xor(a2, 32);
  a3 += __shfl_xor(a3, 16); a3 += __shfl_xor(a3, 32);
  if (lane < 16) {
    int c0 = head * NHID + cl * 4;
    float4 bv = *(const float4*)&b1[c0];
    float v0 = a0 + bv.x, v1 = a1 + bv.y, v2 = a2 + bv.z, v3 = a3 + bv.w;
    v0 = v0 > 0.f ? v0 : (__expf(v0) - 1.f);
    v1 = v1 > 0.f ? v1 : (__expf(v1) - 1.f);
    v2 = v2 > 0.f ? v2 : (__expf(v2) - 1.f);
    v3 = v3 > 0.f ? v3 : (__expf(v3) - 1.f);
    ushort4 o = make_ushort4(f2bf(v0), f2bf(v1), f2bf(v2), f2bf(v3));
    *(ushort4*)&out1b[(size_t)n * D1 + c0] = o;
  }
}

// ---------------- GEMM2 (MFMA): h2(f32) = out1b @ W2 (+pad), fused alpha2 ----------------
__global__ __launch_bounds__(256) void gemm2_mfma(const unsigned short* __restrict__ ab,
                                                  const unsigned short* __restrict__ wb2t,
                                                  const float* __restrict__ a_src2,
                                                  const float* __restrict__ a_dst2,
                                                  float* __restrict__ h2,
                                                  float* __restrict__ asrc,
                                                  float* __restrict__ adst) {
  __shared__ unsigned short As[64 * 64];
  __shared__ unsigned short Bs[48 * 64];
  int tid = threadIdx.x;
  int w = tid >> 6, lane = tid & 63;
  int row0 = blockIdx.x * 64;
  int cl = lane & 15, hi = lane >> 4;
  f32x4 acc[3] = {};
  for (int k0 = 0; k0 < D1; k0 += 64) {
#pragma unroll
    for (int c = 0; c < 2; ++c) {
      int slot = c * 256 + tid;
      int r = slot >> 3;
      int q = (slot & 7) ^ (r & 7);
      gload16(ab + (size_t)(row0 + r) * D1 + k0 + q * 8, (char*)As + (c * 256 + w * 64) * 16);
    }
    {
      int r = tid >> 3;
      int q = (tid & 7) ^ (r & 7);
      gload16(wb2t + (size_t)r * D1 + k0 + q * 8, (char*)Bs + (w * 64) * 16);
      if (tid < 128) {
        int slot2 = 256 + tid;
        int r2 = slot2 >> 3;
        int q2 = (slot2 & 7) ^ (r2 & 7);
        gload16(wb2t + (size_t)r2 * D1 + k0 + q2 * 8, (char*)Bs + ((256 + w * 64)) * 16);
      }
    }
    __syncthreads();
#pragma unroll
    for (int kk = 0; kk < 2; ++kk) {
      int ra = w * 16 + cl;
      bf16x8 a = *(const bf16x8*)&As[ra * 64 + (((kk * 4 + hi) ^ (ra & 7)) << 3)];
#pragma unroll
      for (int n = 0; n < 3; ++n) {
        int rb = n * 16 + cl;
        bf16x8 b = *(const bf16x8*)&Bs[rb * 64 + (((kk * 4 + hi) ^ (rb & 7)) << 3)];
        acc[n] = __builtin_amdgcn_mfma_f32_16x16x32_bf16(a, b, acc[n], 0, 0, 0);
      }
    }
    __syncthreads();
  }
  float asv[3], adv[3];
#pragma unroll
  for (int n = 0; n < 3; ++n) {
    int c = n * 16 + cl;
    asv[n] = (c < NCLS) ? a_src2[c] : 0.f;
    adv[n] = (c < NCLS) ? a_dst2[c] : 0.f;
  }
#pragma unroll
  for (int r = 0; r < 4; ++r) {
    int grow = row0 + w * 16 + hi * 4 + r;
    float ps = acc[0][r] * asv[0] + acc[1][r] * asv[1] + acc[2][r] * asv[2];
    float pd = acc[0][r] * adv[0] + acc[1][r] * adv[1] + acc[2][r] * adv[2];
#pragma unroll
    for (int o = 8; o > 0; o >>= 1) { ps += __shfl_xor(ps, o); pd += __shfl_xor(pd, o); }
    if (grow < N_NODES) {
#pragma unroll
      for (int n = 0; n < 3; ++n) {
        int c = n * 16 + cl;
        if (c < NCLS) h2[(size_t)grow * NCLS + c] = acc[n][r];
      }
      if (cl == 0) { asrc[grow] = ps; adst[grow] = pd; }
    }
  }
}

// ---------------- agg2: LDS alpha + f32x2 gather (3 edges/iter) + b2 + log_softmax ----------------
__global__ __launch_bounds__(256) void agg2_kernel(const int* __restrict__ offsets,
                                                   const int* __restrict__ edge_src,
                                                   const float* __restrict__ asrc,
                                                   const float* __restrict__ adst,
                                                   const float* __restrict__ h2,
                                                   const float* __restrict__ b2,
                                                   float* __restrict__ out) {
  __shared__ float lalpha[4][MAXD];
  __shared__ int   lsoff[4][MAXD];
  int w = threadIdx.x >> 6;
  int lane = threadIdx.x & 63;
  int n = blockIdx.x * 4 + w;
  int base = offsets[n];
  int deg = offsets[n + 1] - base;
  int degc = min(deg, MAXD);
  int degp = ((degc + 2) / 3) * 3;

  float advv = adst[n];
  float m = -INFINITY;
  for (int e = lane; e < deg; e += 64) {
    int s = edge_src[base + e];
    float ev = lrelu(asrc[s] + advv);
    if (e < MAXD) { lsoff[w][e] = s * (NCLS * 4); lalpha[w][e] = ev; }
    m = fmaxf(m, ev);
  }
  m = wave_max(m);
  float ssum = 0.f;
  for (int e = lane; e < deg; e += 64) {
    float ev;
    if (e < MAXD) ev = lalpha[w][e];
    else { int s = edge_src[base + e]; ev = lrelu(asrc[s] + advv); }
    ssum += __expf(ev - m);
  }
  float inv = 1.f / (wave_sum(ssum) + 1e-16f);
  for (int e = lane; e < degc; e += 64) lalpha[w][e] = __expf(lalpha[w][e] - m) * inv;
  {
    int e = degc + lane;
    if (e < degp && e < MAXD) { lalpha[w][e] = 0.f; lsoff[w][e] = 0; }
  }
  __builtin_amdgcn_wave_barrier();

  int esub = lane / 20;
  int cg = lane - esub * 20;
  bool act = esub < 3;
  float ax = 0.f, ay = 0.f;
  const char* hb = (const char*)h2 + cg * 8;
  for (int i = 0; i < degp; i += 3) {
    if (act) {
      int slot = i + esub;
      float a = lalpha[w][slot];
      int so = lsoff[w][slot];
      float2 hv = *(const float2*)(hb + so);
      ax += a * hv.x; ay += a * hv.y;
    }
  }
  for (int e = MAXD + esub; e < deg; e += 3) {   // guard, never runs
    if (act) {
      int s = edge_src[base + e];
      float a = __expf(lrelu(asrc[s] + advv) - m) * inv;
      float2 hv = *(const float2*)(hb + (size_t)s * (NCLS * 4));
      ax += a * hv.x; ay += a * hv.y;
    }
  }
  float ax1 = __shfl(ax, lane + 20), ax2 = __shfl(ax, lane + 40);
  float ay1 = __shfl(ay, lane + 20), ay2 = __shfl(ay, lane + 40);
  float v0 = -INFINITY, v1 = -INFINITY;
  if (lane < 20) {
    v0 = ax + ax1 + ax2 + b2[2 * cg];
    v1 = ay + ay1 + ay2 + b2[2 * cg + 1];
  }
  float m2 = wave_max(fmaxf(v0, v1));
  float se = wave_sum(lane < 20 ? __expf(v0 - m2) + __expf(v1 - m2) : 0.f);
  if (lane < 20) {
    float ls = logf(se);
    *(float2*)&out[(size_t)n * NCLS + 2 * cg] = make_float2(v0 - m2 - ls, v1 - m2 - ls);
  }
}

extern "C" void kernel_launch(void* const* d_in, const int* in_sizes, int n_in,
                              void* d_out, int out_size, void* d_ws, size_t ws_size,
                              hipStream_t stream) {
  const float* x   = (const float*)d_in[0];
  const int*   ei  = (const int*)d_in[1];
  const float* W1  = (const float*)d_in[2];
  const float* as1 = (const float*)d_in[3];
  const float* ad1 = (const float*)d_in[4];
  const float* b1  = (const float*)d_in[5];
  const float* W2  = (const float*)d_in[6];
  const float* as2 = (const float*)d_in[7];
  const float* ad2 = (const float*)d_in[8];
  const float* b2  = (const float*)d_in[9];
  float* out = (float*)d_out;

  char* ws = (char*)d_ws;
  size_t off = 0;
  auto alloc = [&](size_t bytes) -> char* {
    char* p = ws + off;
    off += (bytes + 255) & ~(size_t)255;
    return p;
  };
  int* deg      = (int*)alloc((size_t)N_NODES * 4);
  int* cursor   = (int*)alloc((size_t)N_NODES * 4);
  int* offsets  = (int*)alloc((size_t)(N_NODES + 1) * 4);
  int* edge_src = (int*)alloc((size_t)EP * 4);
  unsigned short* xb    = (unsigned short*)alloc((size_t)MPAD * F_IN * 2);
  unsigned short* wb1t  = (unsigned short*)alloc((size_t)D1 * F_IN * 2);
  unsigned short* wb2t  = (unsigned short*)alloc((size_t)48 * D1 * 2);
  unsigned short* h1b   = (unsigned short*)alloc((size_t)N_NODES * D1 * 2);
  unsigned short* out1b = (unsigned short*)alloc((size_t)MPAD * D1 * 2);
  float* asrc1  = (float*)alloc((size_t)N_NODES * H1 * 4);
  float* adst1  = (float*)alloc((size_t)N_NODES * H1 * 4);
  float* h2     = (float*)alloc((size_t)N_NODES * NCLS * 4);
  float* asrc2  = (float*)alloc((size_t)N_NODES * 4);
  float* adst2  = (float*)alloc((size_t)N_NODES * 4);

  prep_kernel<<<PB_PAD, 256, 0, stream>>>(x, W1, W2, xb, wb1t, wb2t, deg, cursor, out1b);
  count_deg<<<(EP + 255) / 256, 256, 0, stream>>>(ei, deg);
  scan_kernel<<<1, SCAN_T, 0, stream>>>(deg, offsets);
  scatter_edges<<<(EP + 255) / 256, 256, 0, stream>>>(ei, offsets, cursor, edge_src);

  gemm1_mfma<<<157 * 4, 256, 0, stream>>>(xb, wb1t, as1, ad1, h1b, asrc1, adst1);
  agg1_kernel<<<(N_NODES / 4) * 8, 256, 0, stream>>>(offsets, edge_src, asrc1, adst1, h1b, b1, out1b);

  gemm2_mfma<<<MPAD / 64, 256, 0, stream>>>(out1b, wb2t, as2, ad2, h2, asrc2, adst2);
  agg2_kernel<<<N_NODES / 4, 256, 0, stream>>>(offsets, edge_src, asrc2, adst2, h2, b2, out);
}

// Round 12
// 162.467 us; speedup vs baseline: 1.1829x; 1.1829x over previous
//
#include <hip/hip_runtime.h>
#include <hip/hip_bf16.h>
#include <math.h>

#define N_NODES 20000
#define MPAD 20096               // 157*128
#define N_EDGES 320000
#define EP (N_EDGES + N_NODES)   // 340000
#define F_IN 256
#define NHID 64
#define H1 8
#define D1 512
#define NCLS 40
#define NEG_SLOPE 0.2f
#define MAXD 128

typedef __attribute__((ext_vector_type(8))) short bf16x8;
typedef __attribute__((ext_vector_type(4))) float f32x4;

__device__ __forceinline__ float wave_max(float v) {
#pragma unroll
  for (int o = 32; o > 0; o >>= 1) v = fmaxf(v, __shfl_xor(v, o));
  return v;
}
__device__ __forceinline__ float wave_sum(float v) {
#pragma unroll
  for (int o = 32; o > 0; o >>= 1) v += __shfl_xor(v, o);
  return v;
}
__device__ __forceinline__ unsigned short f2bf(float f) {
  union { float f; unsigned int i; } c; c.f = f;
  unsigned int x = c.i;
  return (unsigned short)((x + 0x7fffu + ((x >> 16) & 1u)) >> 16);  // RNE
}
__device__ __forceinline__ float asf(unsigned int u) {
  union { unsigned int i; float f; } c; c.i = u; return c.f;
}
__device__ __forceinline__ float lrelu(float x) { return x > 0.f ? x : NEG_SLOPE * x; }

__device__ __forceinline__ void gload16(const void* g, void* l) {
  __builtin_amdgcn_global_load_lds((const __attribute__((address_space(1))) void*)g,
                                   (__attribute__((address_space(3))) void*)l, 16, 0, 0);
}

// ---------------- fused prep ----------------
#define PB_CONV 2512             // MPAD*F_IN/8/256
#define PB_TW1  (PB_CONV + 32)
#define PB_TW2  (PB_TW1 + 96)
#define PB_ZERO (PB_TW2 + 157)
#define PB_PAD  (PB_ZERO + 24)
__global__ __launch_bounds__(256) void prep_kernel(const float* __restrict__ x,
                                                   const float* __restrict__ W1,
                                                   const float* __restrict__ W2,
                                                   unsigned short* __restrict__ xb,
                                                   unsigned short* __restrict__ wb1t,
                                                   unsigned short* __restrict__ wb2t,
                                                   int* __restrict__ deg,
                                                   int* __restrict__ cursor,
                                                   unsigned short* __restrict__ out1b) {
  __shared__ float tsh[64][65];
  int bid = blockIdx.x;
  int t = threadIdx.x;
  if (bid < PB_CONV) {
    size_t base = ((size_t)bid * 256 + t) * 8;
    int row = (int)(base >> 8);
    ushort4 o0, o1;
    if (row < N_NODES) {
      float4 v0 = *(const float4*)&x[base];
      float4 v1 = *(const float4*)&x[base + 4];
      o0 = make_ushort4(f2bf(v0.x), f2bf(v0.y), f2bf(v0.z), f2bf(v0.w));
      o1 = make_ushort4(f2bf(v1.x), f2bf(v1.y), f2bf(v1.z), f2bf(v1.w));
    } else {
      o0 = make_ushort4(0, 0, 0, 0); o1 = o0;
    }
    *(ushort4*)&xb[base] = o0;
    *(ushort4*)&xb[base + 4] = o1;
  } else if (bid < PB_TW1) {
    int b2 = bid - PB_CONV;
    int bk = b2 & 3, bn = b2 >> 2;
    int tr = t >> 4, tc4 = (t & 15) * 4;
#pragma unroll
    for (int i = 0; i < 4; ++i) {
      int k = i * 16 + tr;
      float4 v = *(const float4*)&W1[(size_t)(bk * 64 + k) * D1 + bn * 64 + tc4];
      tsh[k][tc4] = v.x; tsh[k][tc4 + 1] = v.y; tsh[k][tc4 + 2] = v.z; tsh[k][tc4 + 3] = v.w;
    }
    __syncthreads();
#pragma unroll
    for (int i = 0; i < 4; ++i) {
      int n = i * 16 + tr;
      ushort4 o = make_ushort4(f2bf(tsh[tc4][n]), f2bf(tsh[tc4 + 1][n]),
                               f2bf(tsh[tc4 + 2][n]), f2bf(tsh[tc4 + 3][n]));
      *(ushort4*)&wb1t[(size_t)(bn * 64 + n) * F_IN + bk * 64 + tc4] = o;
    }
  } else if (bid < PB_TW2) {
    int idx = (bid - PB_TW1) * 256 + t;
    int c = idx >> 9, k = idx & 511;
    wb2t[idx] = f2bf((c < NCLS) ? W2[(size_t)k * NCLS + c] : 0.f);
  } else if (bid < PB_ZERO) {
    int idx = (bid - PB_TW2) * 256 + t;
    if (idx < N_NODES) deg[idx] = 0;
    else if (idx < 2 * N_NODES) cursor[idx - N_NODES] = 0;
  } else {
    int idx = (bid - PB_ZERO) * 256 + t;
    uint4 z = make_uint4(0, 0, 0, 0);
    *(uint4*)((char*)out1b + (size_t)N_NODES * D1 * 2 + (size_t)idx * 16) = z;
  }
}

// ---------------- CSR build ----------------
__global__ void count_deg(const int* __restrict__ ei, int* __restrict__ deg) {
  int e = blockIdx.x * blockDim.x + threadIdx.x;
  if (e >= EP) return;
  int dst = (e < N_EDGES) ? ei[N_EDGES + e] : (e - N_EDGES);
  atomicAdd(&deg[dst], 1);
}

#define SCAN_T 1024
#define SCAN_CHUNK 20
__global__ __launch_bounds__(1024) void scan_kernel(const int* __restrict__ deg,
                                                    int* __restrict__ offsets) {
  __shared__ int wsum[16];
  int t = threadIdx.x;
  int w = t >> 6, lane = t & 63;
  int lo = t * SCAN_CHUNK;
  int hi = min(lo + SCAN_CHUNK, N_NODES);
  int s = 0;
  for (int i = lo; i < hi; ++i) s += deg[i];
  int incl = s;
#pragma unroll
  for (int o = 1; o < 64; o <<= 1) {
    int v = __shfl_up(incl, o);
    if (lane >= o) incl += v;
  }
  if (lane == 63) wsum[w] = incl;
  __syncthreads();
  if (t == 0) {
    int run = 0;
#pragma unroll
    for (int i = 0; i < 16; ++i) { int v = wsum[i]; wsum[i] = run; run += v; }
  }
  __syncthreads();
  int off = wsum[w] + incl - s;
  for (int i = lo; i < hi; ++i) { offsets[i] = off; off += deg[i]; }
  if (hi == N_NODES && lo < N_NODES) offsets[N_NODES] = off;
}

__global__ void scatter_edges(const int* __restrict__ ei, const int* __restrict__ offsets,
                              int* __restrict__ cursor, int* __restrict__ edge_src) {
  int e = blockIdx.x * blockDim.x + threadIdx.x;
  if (e >= EP) return;
  int src, dst;
  if (e < N_EDGES) { src = ei[e]; dst = ei[N_EDGES + e]; }
  else             { src = dst = e - N_EDGES; }
  int pos = offsets[dst] + atomicAdd(&cursor[dst], 1);
  edge_src[pos] = src;
}

// ---------------- GEMM1 (MFMA): h1b = xb @ W1, fused alpha1 logits. BK=64 ----------------
__global__ __launch_bounds__(256) void gemm1_mfma(const unsigned short* __restrict__ xb,
                                                  const unsigned short* __restrict__ wb1t,
                                                  const float* __restrict__ a_src,
                                                  const float* __restrict__ a_dst,
                                                  unsigned short* __restrict__ h1b,
                                                  float* __restrict__ asrc,
                                                  float* __restrict__ adst) {
  __shared__ unsigned short As[128 * 64];
  __shared__ unsigned short Bs[128 * 64];
  int tid = threadIdx.x;
  int w = tid >> 6, lane = tid & 63;
  int bn = blockIdx.x & 3, bm = blockIdx.x >> 2;
  int row0 = bm * 128, col0 = bn * 128;
  int wr = w >> 1, wc = w & 1;
  int cl = lane & 15, hi = lane >> 4;
  f32x4 acc[4][4] = {};
  for (int k0 = 0; k0 < F_IN; k0 += 64) {
#pragma unroll
    for (int c = 0; c < 4; ++c) {
      int slot = c * 256 + tid;
      int r = slot >> 3;
      int q = (slot & 7) ^ (r & 7);
      gload16(xb + (size_t)(row0 + r) * F_IN + k0 + q * 8, (char*)As + (c * 256 + w * 64) * 16);
      gload16(wb1t + (size_t)(col0 + r) * F_IN + k0 + q * 8, (char*)Bs + (c * 256 + w * 64) * 16);
    }
    __syncthreads();
#pragma unroll
    for (int kk = 0; kk < 2; ++kk) {
      bf16x8 a[4], b[4];
#pragma unroll
      for (int m = 0; m < 4; ++m) {
        int r = wr * 64 + m * 16 + cl;
        a[m] = *(const bf16x8*)&As[r * 64 + ((((kk * 4 + hi)) ^ (r & 7)) << 3)];
      }
#pragma unroll
      for (int n = 0; n < 4; ++n) {
        int r = wc * 64 + n * 16 + cl;
        b[n] = *(const bf16x8*)&Bs[r * 64 + ((((kk * 4 + hi)) ^ (r & 7)) << 3)];
      }
#pragma unroll
      for (int m = 0; m < 4; ++m)
#pragma unroll
        for (int n = 0; n < 4; ++n)
          acc[m][n] = __builtin_amdgcn_mfma_f32_16x16x32_bf16(a[m], b[n], acc[m][n], 0, 0, 0);
    }
    __syncthreads();
  }
  int head = bn * 2 + wc;
  float asv[4], adv[4];
#pragma unroll
  for (int n = 0; n < 4; ++n) {
    asv[n] = a_src[head * 64 + n * 16 + cl];
    adv[n] = a_dst[head * 64 + n * 16 + cl];
  }
#pragma unroll
  for (int m = 0; m < 4; ++m) {
#pragma unroll
    for (int r = 0; r < 4; ++r) {
      int grow = row0 + wr * 64 + m * 16 + hi * 4 + r;
      float ps = acc[m][0][r] * asv[0] + acc[m][1][r] * asv[1] +
                 acc[m][2][r] * asv[2] + acc[m][3][r] * asv[3];
      float pd = acc[m][0][r] * adv[0] + acc[m][1][r] * adv[1] +
                 acc[m][2][r] * adv[2] + acc[m][3][r] * adv[3];
#pragma unroll
      for (int o = 8; o > 0; o >>= 1) { ps += __shfl_xor(ps, o); pd += __shfl_xor(pd, o); }
      if (grow < N_NODES) {
#pragma unroll
        for (int n = 0; n < 4; ++n)
          h1b[(size_t)grow * D1 + col0 + wc * 64 + n * 16 + cl] = f2bf(acc[m][n][r]);
        if (cl == 0) { asrc[grow * H1 + head] = ps; adst[grow * H1 + head] = pd; }
      }
    }
  }
}

// ---------------- alpha1: node-parallel softmax -> unnormalized alpha (head-major) + inv ----------------
// wave per node; lane = (edge-slot et = lane>>3, head h = lane&7). Unrolled k<8 covers deg<=64
// with static register indices; guard loops recompute for deg>64.
__global__ __launch_bounds__(256) void alpha1_kernel(const int* __restrict__ offsets,
                                                     const int* __restrict__ edge_src,
                                                     const float* __restrict__ asrc,
                                                     const float* __restrict__ adst,
                                                     float* __restrict__ alphaE,
                                                     float* __restrict__ inv1) {
  int w = threadIdx.x >> 6, lane = threadIdx.x & 63;
  int n = blockIdx.x * 4 + w;
  int base = offsets[n];
  int deg = offsets[n + 1] - base;
  int h = lane & 7, et = lane >> 3;
  float adv = adst[n * H1 + h];
  float evr[8];
  float m = -INFINITY;
#pragma unroll
  for (int k = 0; k < 8; ++k) {
    int e = et + k * 8;
    float ev = -INFINITY;
    if (e < deg) ev = lrelu(asrc[edge_src[base + e] * H1 + h] + adv);
    evr[k] = ev;
    m = fmaxf(m, ev);
  }
  for (int e = et + 64; e < deg; e += 8)   // guard, never runs for this graph
    m = fmaxf(m, lrelu(asrc[edge_src[base + e] * H1 + h] + adv));
  m = fmaxf(m, __shfl_xor(m, 8));
  m = fmaxf(m, __shfl_xor(m, 16));
  m = fmaxf(m, __shfl_xor(m, 32));
  float ss = 0.f;
#pragma unroll
  for (int k = 0; k < 8; ++k) {
    int e = et + k * 8;
    if (e < deg) {
      float a = __expf(evr[k] - m);
      alphaE[(size_t)h * EP + base + e] = a;
      ss += a;
    }
  }
  for (int e = et + 64; e < deg; e += 8) { // guard
    float a = __expf(lrelu(asrc[edge_src[base + e] * H1 + h] + adv) - m);
    alphaE[(size_t)h * EP + base + e] = a;
    ss += a;
  }
  ss += __shfl_xor(ss, 8);
  ss += __shfl_xor(ss, 16);
  ss += __shfl_xor(ss, 32);
  if (et == 0) inv1[n * H1 + h] = 1.f / (ss + 1e-16f);
}

// ---------------- agg1 gather: head-sliced XCD-affine, no LDS/shfl/barriers ----------------
// bid&7 = head (round-robin block->XCD => per-XCD h1b re-read set = 2.56MB < 4MB L2).
// wave = 8 nodes x 1 head; 8 lanes/node x 16B = head's full 128B slice per edge.
__global__ __launch_bounds__(256) void agg1_gather(const int* __restrict__ offsets,
                                                   const int* __restrict__ edge_src,
                                                   const float* __restrict__ alphaE,
                                                   const float* __restrict__ inv1,
                                                   const unsigned short* __restrict__ h1b,
                                                   const float* __restrict__ b1,
                                                   unsigned short* __restrict__ out1b) {
  int w = threadIdx.x >> 6, lane = threadIdx.x & 63;
  int bid = blockIdx.x;
  int head = bid & 7;
  int ng = bid >> 3;                 // 0..624
  int sub = lane >> 3, cl = lane & 7;
  int n = ng * 32 + w * 8 + sub;
  int base = offsets[n];
  int deg = offsets[n + 1] - base;
  const float* aE = alphaE + (size_t)head * EP + base;
  const int* es = edge_src + base;
  const char* hb = (const char*)h1b + head * 128 + cl * 16;
  float acc[8] = {};
  int e = 0;
  for (; e + 1 < deg; e += 2) {      // unroll x2: two independent row loads in flight
    float a0 = aE[e], a1 = aE[e + 1];
    int s0 = es[e], s1 = es[e + 1];
    uint4 u0 = *(const uint4*)(hb + ((size_t)s0 << 10));
    uint4 u1 = *(const uint4*)(hb + ((size_t)s1 << 10));
#pragma unroll
    for (int j = 0; j < 4; ++j) {
      unsigned int x0 = ((const unsigned int*)&u0)[j];
      unsigned int x1 = ((const unsigned int*)&u1)[j];
      acc[2 * j]     += a0 * asf(x0 << 16) + a1 * asf(x1 << 16);
      acc[2 * j + 1] += a0 * asf(x0 & 0xffff0000u) + a1 * asf(x1 & 0xffff0000u);
    }
  }
  if (e < deg) {
    float a = aE[e];
    int s = es[e];
    uint4 uv = *(const uint4*)(hb + ((size_t)s << 10));
#pragma unroll
    for (int j = 0; j < 4; ++j) {
      unsigned int u = ((const unsigned int*)&uv)[j];
      acc[2 * j]     += a * asf(u << 16);
      acc[2 * j + 1] += a * asf(u & 0xffff0000u);
    }
  }
  float inv = inv1[n * H1 + head];
  int c0 = head * NHID + cl * 8;
  float4 b0 = *(const float4*)&b1[c0];
  float4 b4 = *(const float4*)&b1[c0 + 4];
  float v[8];
  v[0] = acc[0] * inv + b0.x; v[1] = acc[1] * inv + b0.y;
  v[2] = acc[2] * inv + b0.z; v[3] = acc[3] * inv + b0.w;
  v[4] = acc[4] * inv + b4.x; v[5] = acc[5] * inv + b4.y;
  v[6] = acc[6] * inv + b4.z; v[7] = acc[7] * inv + b4.w;
#pragma unroll
  for (int j = 0; j < 8; ++j) v[j] = v[j] > 0.f ? v[j] : (__expf(v[j]) - 1.f);  // ELU
  ushort4 o0 = make_ushort4(f2bf(v[0]), f2bf(v[1]), f2bf(v[2]), f2bf(v[3]));
  ushort4 o1 = make_ushort4(f2bf(v[4]), f2bf(v[5]), f2bf(v[6]), f2bf(v[7]));
  *(ushort4*)&out1b[(size_t)n * D1 + c0] = o0;
  *(ushort4*)&out1b[(size_t)n * D1 + c0 + 4] = o1;
}

// ---------------- GEMM2 (MFMA): h2(f32) = out1b @ W2 (+pad), fused alpha2 ----------------
__global__ __launch_bounds__(256) void gemm2_mfma(const unsigned short* __restrict__ ab,
                                                  const unsigned short* __restrict__ wb2t,
                                                  const float* __restrict__ a_src2,
                                                  const float* __restrict__ a_dst2,
                                                  float* __restrict__ h2,
                                                  float* __restrict__ asrc,
                                                  float* __restrict__ adst) {
  __shared__ unsigned short As[64 * 64];
  __shared__ unsigned short Bs[48 * 64];
  int tid = threadIdx.x;
  int w = tid >> 6, lane = tid & 63;
  int row0 = blockIdx.x * 64;
  int cl = lane & 15, hi = lane >> 4;
  f32x4 acc[3] = {};
  for (int k0 = 0; k0 < D1; k0 += 64) {
#pragma unroll
    for (int c = 0; c < 2; ++c) {
      int slot = c * 256 + tid;
      int r = slot >> 3;
      int q = (slot & 7) ^ (r & 7);
      gload16(ab + (size_t)(row0 + r) * D1 + k0 + q * 8, (char*)As + (c * 256 + w * 64) * 16);
    }
    {
      int r = tid >> 3;
      int q = (tid & 7) ^ (r & 7);
      gload16(wb2t + (size_t)r * D1 + k0 + q * 8, (char*)Bs + (w * 64) * 16);
      if (tid < 128) {
        int slot2 = 256 + tid;
        int r2 = slot2 >> 3;
        int q2 = (slot2 & 7) ^ (r2 & 7);
        gload16(wb2t + (size_t)r2 * D1 + k0 + q2 * 8, (char*)Bs + ((256 + w * 64)) * 16);
      }
    }
    __syncthreads();
#pragma unroll
    for (int kk = 0; kk < 2; ++kk) {
      int ra = w * 16 + cl;
      bf16x8 a = *(const bf16x8*)&As[ra * 64 + (((kk * 4 + hi) ^ (ra & 7)) << 3)];
#pragma unroll
      for (int n = 0; n < 3; ++n) {
        int rb = n * 16 + cl;
        bf16x8 b = *(const bf16x8*)&Bs[rb * 64 + (((kk * 4 + hi) ^ (rb & 7)) << 3)];
        acc[n] = __builtin_amdgcn_mfma_f32_16x16x32_bf16(a, b, acc[n], 0, 0, 0);
      }
    }
    __syncthreads();
  }
  float asv[3], adv[3];
#pragma unroll
  for (int n = 0; n < 3; ++n) {
    int c = n * 16 + cl;
    asv[n] = (c < NCLS) ? a_src2[c] : 0.f;
    adv[n] = (c < NCLS) ? a_dst2[c] : 0.f;
  }
#pragma unroll
  for (int r = 0; r < 4; ++r) {
    int grow = row0 + w * 16 + hi * 4 + r;
    float ps = acc[0][r] * asv[0] + acc[1][r] * asv[1] + acc[2][r] * asv[2];
    float pd = acc[0][r] * adv[0] + acc[1][r] * adv[1] + acc[2][r] * adv[2];
#pragma unroll
    for (int o = 8; o > 0; o >>= 1) { ps += __shfl_xor(ps, o); pd += __shfl_xor(pd, o); }
    if (grow < N_NODES) {
#pragma unroll
      for (int n = 0; n < 3; ++n) {
        int c = n * 16 + cl;
        if (c < NCLS) h2[(size_t)grow * NCLS + c] = acc[n][r];
      }
      if (cl == 0) { asrc[grow] = ps; adst[grow] = pd; }
    }
  }
}

// ---------------- agg2: LDS alpha + f32x2 gather (3 edges/iter) + b2 + log_softmax ----------------
__global__ __launch_bounds__(256) void agg2_kernel(const int* __restrict__ offsets,
                                                   const int* __restrict__ edge_src,
                                                   const float* __restrict__ asrc,
                                                   const float* __restrict__ adst,
                                                   const float* __restrict__ h2,
                                                   const float* __restrict__ b2,
                                                   float* __restrict__ out) {
  __shared__ float lalpha[4][MAXD];
  __shared__ int   lsoff[4][MAXD];
  int w = threadIdx.x >> 6;
  int lane = threadIdx.x & 63;
  int n = blockIdx.x * 4 + w;
  int base = offsets[n];
  int deg = offsets[n + 1] - base;
  int degc = min(deg, MAXD);
  int degp = ((degc + 2) / 3) * 3;

  float advv = adst[n];
  float m = -INFINITY;
  for (int e = lane; e < deg; e += 64) {
    int s = edge_src[base + e];
    float ev = lrelu(asrc[s] + advv);
    if (e < MAXD) { lsoff[w][e] = s * (NCLS * 4); lalpha[w][e] = ev; }
    m = fmaxf(m, ev);
  }
  m = wave_max(m);
  float ssum = 0.f;
  for (int e = lane; e < deg; e += 64) {
    float ev;
    if (e < MAXD) ev = lalpha[w][e];
    else { int s = edge_src[base + e]; ev = lrelu(asrc[s] + advv); }
    ssum += __expf(ev - m);
  }
  float inv = 1.f / (wave_sum(ssum) + 1e-16f);
  for (int e = lane; e < degc; e += 64) lalpha[w][e] = __expf(lalpha[w][e] - m) * inv;
  {
    int e = degc + lane;
    if (e < degp && e < MAXD) { lalpha[w][e] = 0.f; lsoff[w][e] = 0; }
  }
  __builtin_amdgcn_wave_barrier();

  int esub = lane / 20;
  int cg = lane - esub * 20;
  bool act = esub < 3;
  float ax = 0.f, ay = 0.f;
  const char* hb = (const char*)h2 + cg * 8;
  for (int i = 0; i < degp; i += 3) {
    if (act) {
      int slot = i + esub;
      float a = lalpha[w][slot];
      int so = lsoff[w][slot];
      float2 hv = *(const float2*)(hb + so);
      ax += a * hv.x; ay += a * hv.y;
    }
  }
  for (int e = MAXD + esub; e < deg; e += 3) {   // guard, never runs
    if (act) {
      int s = edge_src[base + e];
      float a = __expf(lrelu(asrc[s] + advv) - m) * inv;
      float2 hv = *(const float2*)(hb + (size_t)s * (NCLS * 4));
      ax += a * hv.x; ay += a * hv.y;
    }
  }
  float ax1 = __shfl(ax, lane + 20), ax2 = __shfl(ax, lane + 40);
  float ay1 = __shfl(ay, lane + 20), ay2 = __shfl(ay, lane + 40);
  float v0 = -INFINITY, v1 = -INFINITY;
  if (lane < 20) {
    v0 = ax + ax1 + ax2 + b2[2 * cg];
    v1 = ay + ay1 + ay2 + b2[2 * cg + 1];
  }
  float m2 = wave_max(fmaxf(v0, v1));
  float se = wave_sum(lane < 20 ? __expf(v0 - m2) + __expf(v1 - m2) : 0.f);
  if (lane < 20) {
    float ls = logf(se);
    *(float2*)&out[(size_t)n * NCLS + 2 * cg] = make_float2(v0 - m2 - ls, v1 - m2 - ls);
  }
}

extern "C" void kernel_launch(void* const* d_in, const int* in_sizes, int n_in,
                              void* d_out, int out_size, void* d_ws, size_t ws_size,
                              hipStream_t stream) {
  const float* x   = (const float*)d_in[0];
  const int*   ei  = (const int*)d_in[1];
  const float* W1  = (const float*)d_in[2];
  const float* as1 = (const float*)d_in[3];
  const float* ad1 = (const float*)d_in[4];
  const float* b1  = (const float*)d_in[5];
  const float* W2  = (const float*)d_in[6];
  const float* as2 = (const float*)d_in[7];
  const float* ad2 = (const float*)d_in[8];
  const float* b2  = (const float*)d_in[9];
  float* out = (float*)d_out;

  char* ws = (char*)d_ws;
  size_t off = 0;
  auto alloc = [&](size_t bytes) -> char* {
    char* p = ws + off;
    off += (bytes + 255) & ~(size_t)255;
    return p;
  };
  int* deg      = (int*)alloc((size_t)N_NODES * 4);
  int* cursor   = (int*)alloc((size_t)N_NODES * 4);
  int* offsets  = (int*)alloc((size_t)(N_NODES + 1) * 4);
  int* edge_src = (int*)alloc((size_t)EP * 4);
  unsigned short* xb    = (unsigned short*)alloc((size_t)MPAD * F_IN * 2);
  unsigned short* wb1t  = (unsigned short*)alloc((size_t)D1 * F_IN * 2);
  unsigned short* wb2t  = (unsigned short*)alloc((size_t)48 * D1 * 2);
  unsigned short* h1b   = (unsigned short*)alloc((size_t)N_NODES * D1 * 2);
  unsigned short* out1b = (unsigned short*)alloc((size_t)MPAD * D1 * 2);
  float* asrc1  = (float*)alloc((size_t)N_NODES * H1 * 4);
  float* adst1  = (float*)alloc((size_t)N_NODES * H1 * 4);
  float* alphaE = (float*)alloc((size_t)H1 * EP * 4);
  float* inv1   = (float*)alloc((size_t)N_NODES * H1 * 4);
  float* h2     = (float*)alloc((size_t)N_NODES * NCLS * 4);
  float* asrc2  = (float*)alloc((size_t)N_NODES * 4);
  float* adst2  = (float*)alloc((size_t)N_NODES * 4);

  prep_kernel<<<PB_PAD, 256, 0, stream>>>(x, W1, W2, xb, wb1t, wb2t, deg, cursor, out1b);
  count_deg<<<(EP + 255) / 256, 256, 0, stream>>>(ei, deg);
  scan_kernel<<<1, SCAN_T, 0, stream>>>(deg, offsets);
  scatter_edges<<<(EP + 255) / 256, 256, 0, stream>>>(ei, offsets, cursor, edge_src);

  gemm1_mfma<<<157 * 4, 256, 0, stream>>>(xb, wb1t, as1, ad1, h1b, asrc1, adst1);
  alpha1_kernel<<<N_NODES / 4, 256, 0, stream>>>(offsets, edge_src, asrc1, adst1, alphaE, inv1);
  agg1_gather<<<(N_NODES / 32) * 8, 256, 0, stream>>>(offsets, edge_src, alphaE, inv1, h1b, b1, out1b);

  gemm2_mfma<<<MPAD / 64, 256, 0, stream>>>(out1b, wb2t, as2, ad2, h2, asrc2, adst2);
  agg2_kernel<<<N_NODES / 4, 256, 0, stream>>>(offsets, edge_src, asrc2, adst2, h2, b2, out);
}

// Round 13
// 154.115 us; speedup vs baseline: 1.2470x; 1.0542x over previous
//
#include <hip/hip_runtime.h>
#include <hip/hip_bf16.h>
#include <math.h>

#define N_NODES 20000
#define MPAD 20096               // 157*128
#define N_EDGES 320000
#define EP (N_EDGES + N_NODES)   // 340000
#define F_IN 256
#define NHID 64
#define H1 8
#define D1 512
#define NCLS 40
#define NEG_SLOPE 0.2f
#define MAXD 128

typedef __attribute__((ext_vector_type(8))) short bf16x8;
typedef __attribute__((ext_vector_type(4))) float f32x4;

__device__ __forceinline__ float wave_max(float v) {
#pragma unroll
  for (int o = 32; o > 0; o >>= 1) v = fmaxf(v, __shfl_xor(v, o));
  return v;
}
__device__ __forceinline__ float wave_sum(float v) {
#pragma unroll
  for (int o = 32; o > 0; o >>= 1) v += __shfl_xor(v, o);
  return v;
}
__device__ __forceinline__ unsigned short f2bf(float f) {
  union { float f; unsigned int i; } c; c.f = f;
  unsigned int x = c.i;
  return (unsigned short)((x + 0x7fffu + ((x >> 16) & 1u)) >> 16);  // RNE
}
__device__ __forceinline__ float asf(unsigned int u) {
  union { unsigned int i; float f; } c; c.i = u; return c.f;
}
__device__ __forceinline__ float lrelu(float x) { return x > 0.f ? x : NEG_SLOPE * x; }

__device__ __forceinline__ void gload16(const void* g, void* l) {
  __builtin_amdgcn_global_load_lds((const __attribute__((address_space(1))) void*)g,
                                   (__attribute__((address_space(3))) void*)l, 16, 0, 0);
}

// ---------------- fused prep ----------------
#define PB_CONV 2512             // MPAD*F_IN/8/256
#define PB_TW1  (PB_CONV + 32)
#define PB_TW2  (PB_TW1 + 96)
#define PB_ZERO (PB_TW2 + 157)
#define PB_PAD  (PB_ZERO + 24)
__global__ __launch_bounds__(256) void prep_kernel(const float* __restrict__ x,
                                                   const float* __restrict__ W1,
                                                   const float* __restrict__ W2,
                                                   unsigned short* __restrict__ xb,
                                                   unsigned short* __restrict__ wb1t,
                                                   unsigned short* __restrict__ wb2t,
                                                   int* __restrict__ deg,
                                                   int* __restrict__ cursor,
                                                   unsigned short* __restrict__ out1b) {
  __shared__ float tsh[64][65];
  int bid = blockIdx.x;
  int t = threadIdx.x;
  if (bid < PB_CONV) {
    size_t base = ((size_t)bid * 256 + t) * 8;
    int row = (int)(base >> 8);
    ushort4 o0, o1;
    if (row < N_NODES) {
      float4 v0 = *(const float4*)&x[base];
      float4 v1 = *(const float4*)&x[base + 4];
      o0 = make_ushort4(f2bf(v0.x), f2bf(v0.y), f2bf(v0.z), f2bf(v0.w));
      o1 = make_ushort4(f2bf(v1.x), f2bf(v1.y), f2bf(v1.z), f2bf(v1.w));
    } else {
      o0 = make_ushort4(0, 0, 0, 0); o1 = o0;
    }
    *(ushort4*)&xb[base] = o0;
    *(ushort4*)&xb[base + 4] = o1;
  } else if (bid < PB_TW1) {
    int b2 = bid - PB_CONV;
    int bk = b2 & 3, bn = b2 >> 2;
    int tr = t >> 4, tc4 = (t & 15) * 4;
#pragma unroll
    for (int i = 0; i < 4; ++i) {
      int k = i * 16 + tr;
      float4 v = *(const float4*)&W1[(size_t)(bk * 64 + k) * D1 + bn * 64 + tc4];
      tsh[k][tc4] = v.x; tsh[k][tc4 + 1] = v.y; tsh[k][tc4 + 2] = v.z; tsh[k][tc4 + 3] = v.w;
    }
    __syncthreads();
#pragma unroll
    for (int i = 0; i < 4; ++i) {
      int n = i * 16 + tr;
      ushort4 o = make_ushort4(f2bf(tsh[tc4][n]), f2bf(tsh[tc4 + 1][n]),
                               f2bf(tsh[tc4 + 2][n]), f2bf(tsh[tc4 + 3][n]));
      *(ushort4*)&wb1t[(size_t)(bn * 64 + n) * F_IN + bk * 64 + tc4] = o;
    }
  } else if (bid < PB_TW2) {
    int idx = (bid - PB_TW1) * 256 + t;
    int c = idx >> 9, k = idx & 511;
    wb2t[idx] = f2bf((c < NCLS) ? W2[(size_t)k * NCLS + c] : 0.f);
  } else if (bid < PB_ZERO) {
    int idx = (bid - PB_TW2) * 256 + t;
    if (idx < N_NODES) deg[idx] = 0;
    else if (idx < 2 * N_NODES) cursor[idx - N_NODES] = 0;
  } else {
    int idx = (bid - PB_ZERO) * 256 + t;
    uint4 z = make_uint4(0, 0, 0, 0);
    *(uint4*)((char*)out1b + (size_t)N_NODES * D1 * 2 + (size_t)idx * 16) = z;
  }
}

// ---------------- CSR build ----------------
__global__ void count_deg(const int* __restrict__ ei, int* __restrict__ deg) {
  int e = blockIdx.x * blockDim.x + threadIdx.x;
  if (e >= EP) return;
  int dst = (e < N_EDGES) ? ei[N_EDGES + e] : (e - N_EDGES);
  atomicAdd(&deg[dst], 1);
}

#define SCAN_T 1024
#define SCAN_CHUNK 20
__global__ __launch_bounds__(1024) void scan_kernel(const int* __restrict__ deg,
                                                    int* __restrict__ offsets) {
  __shared__ int wsum[16];
  int t = threadIdx.x;
  int w = t >> 6, lane = t & 63;
  int lo = t * SCAN_CHUNK;
  int hi = min(lo + SCAN_CHUNK, N_NODES);
  int s = 0;
  for (int i = lo; i < hi; ++i) s += deg[i];
  int incl = s;
#pragma unroll
  for (int o = 1; o < 64; o <<= 1) {
    int v = __shfl_up(incl, o);
    if (lane >= o) incl += v;
  }
  if (lane == 63) wsum[w] = incl;
  __syncthreads();
  if (t == 0) {
    int run = 0;
#pragma unroll
    for (int i = 0; i < 16; ++i) { int v = wsum[i]; wsum[i] = run; run += v; }
  }
  __syncthreads();
  int off = wsum[w] + incl - s;
  for (int i = lo; i < hi; ++i) { offsets[i] = off; off += deg[i]; }
  if (hi == N_NODES && lo < N_NODES) offsets[N_NODES] = off;
}

__global__ void scatter_edges(const int* __restrict__ ei, const int* __restrict__ offsets,
                              int* __restrict__ cursor, int* __restrict__ edge_src) {
  int e = blockIdx.x * blockDim.x + threadIdx.x;
  if (e >= EP) return;
  int src, dst;
  if (e < N_EDGES) { src = ei[e]; dst = ei[N_EDGES + e]; }
  else             { src = dst = e - N_EDGES; }
  int pos = offsets[dst] + atomicAdd(&cursor[dst], 1);
  edge_src[pos] = src;
}

// ---------------- GEMM1 (MFMA): h1b = xb @ W1, fused alpha1 logits. BK=64 ----------------
__global__ __launch_bounds__(256) void gemm1_mfma(const unsigned short* __restrict__ xb,
                                                  const unsigned short* __restrict__ wb1t,
                                                  const float* __restrict__ a_src,
                                                  const float* __restrict__ a_dst,
                                                  unsigned short* __restrict__ h1b,
                                                  float* __restrict__ asrc,
                                                  float* __restrict__ adst) {
  __shared__ unsigned short As[128 * 64];
  __shared__ unsigned short Bs[128 * 64];
  int tid = threadIdx.x;
  int w = tid >> 6, lane = tid & 63;
  int bn = blockIdx.x & 3, bm = blockIdx.x >> 2;
  int row0 = bm * 128, col0 = bn * 128;
  int wr = w >> 1, wc = w & 1;
  int cl = lane & 15, hi = lane >> 4;
  f32x4 acc[4][4] = {};
  for (int k0 = 0; k0 < F_IN; k0 += 64) {
#pragma unroll
    for (int c = 0; c < 4; ++c) {
      int slot = c * 256 + tid;
      int r = slot >> 3;
      int q = (slot & 7) ^ (r & 7);
      gload16(xb + (size_t)(row0 + r) * F_IN + k0 + q * 8, (char*)As + (c * 256 + w * 64) * 16);
      gload16(wb1t + (size_t)(col0 + r) * F_IN + k0 + q * 8, (char*)Bs + (c * 256 + w * 64) * 16);
    }
    __syncthreads();
#pragma unroll
    for (int kk = 0; kk < 2; ++kk) {
      bf16x8 a[4], b[4];
#pragma unroll
      for (int m = 0; m < 4; ++m) {
        int r = wr * 64 + m * 16 + cl;
        a[m] = *(const bf16x8*)&As[r * 64 + ((((kk * 4 + hi)) ^ (r & 7)) << 3)];
      }
#pragma unroll
      for (int n = 0; n < 4; ++n) {
        int r = wc * 64 + n * 16 + cl;
        b[n] = *(const bf16x8*)&Bs[r * 64 + ((((kk * 4 + hi)) ^ (r & 7)) << 3)];
      }
#pragma unroll
      for (int m = 0; m < 4; ++m)
#pragma unroll
        for (int n = 0; n < 4; ++n)
          acc[m][n] = __builtin_amdgcn_mfma_f32_16x16x32_bf16(a[m], b[n], acc[m][n], 0, 0, 0);
    }
    __syncthreads();
  }
  int head = bn * 2 + wc;
  float asv[4], adv[4];
#pragma unroll
  for (int n = 0; n < 4; ++n) {
    asv[n] = a_src[head * 64 + n * 16 + cl];
    adv[n] = a_dst[head * 64 + n * 16 + cl];
  }
#pragma unroll
  for (int m = 0; m < 4; ++m) {
#pragma unroll
    for (int r = 0; r < 4; ++r) {
      int grow = row0 + wr * 64 + m * 16 + hi * 4 + r;
      float ps = acc[m][0][r] * asv[0] + acc[m][1][r] * asv[1] +
                 acc[m][2][r] * asv[2] + acc[m][3][r] * asv[3];
      float pd = acc[m][0][r] * adv[0] + acc[m][1][r] * adv[1] +
                 acc[m][2][r] * adv[2] + acc[m][3][r] * adv[3];
#pragma unroll
      for (int o = 8; o > 0; o >>= 1) { ps += __shfl_xor(ps, o); pd += __shfl_xor(pd, o); }
      if (grow < N_NODES) {
#pragma unroll
        for (int n = 0; n < 4; ++n)
          h1b[(size_t)grow * D1 + col0 + wc * 64 + n * 16 + cl] = f2bf(acc[m][n][r]);
        if (cl == 0) { asrc[grow * H1 + head] = ps; adst[grow * H1 + head] = pd; }
      }
    }
  }
}

// ---------------- alpha1: node-parallel softmax -> unnormalized alpha (head-major) + inv ----------------
__global__ __launch_bounds__(256) void alpha1_kernel(const int* __restrict__ offsets,
                                                     const int* __restrict__ edge_src,
                                                     const float* __restrict__ asrc,
                                                     const float* __restrict__ adst,
                                                     float* __restrict__ alphaE,
                                                     float* __restrict__ inv1) {
  int w = threadIdx.x >> 6, lane = threadIdx.x & 63;
  int n = blockIdx.x * 4 + w;
  int base = offsets[n];
  int deg = offsets[n + 1] - base;
  int h = lane & 7, et = lane >> 3;
  float adv = adst[n * H1 + h];
  float evr[8];
  float m = -INFINITY;
#pragma unroll
  for (int k = 0; k < 8; ++k) {
    int e = et + k * 8;
    float ev = -INFINITY;
    if (e < deg) ev = lrelu(asrc[edge_src[base + e] * H1 + h] + adv);
    evr[k] = ev;
    m = fmaxf(m, ev);
  }
  for (int e = et + 64; e < deg; e += 8)   // guard, never runs for this graph
    m = fmaxf(m, lrelu(asrc[edge_src[base + e] * H1 + h] + adv));
  m = fmaxf(m, __shfl_xor(m, 8));
  m = fmaxf(m, __shfl_xor(m, 16));
  m = fmaxf(m, __shfl_xor(m, 32));
  float ss = 0.f;
#pragma unroll
  for (int k = 0; k < 8; ++k) {
    int e = et + k * 8;
    if (e < deg) {
      float a = __expf(evr[k] - m);
      alphaE[(size_t)h * EP + base + e] = a;
      ss += a;
    }
  }
  for (int e = et + 64; e < deg; e += 8) { // guard
    float a = __expf(lrelu(asrc[edge_src[base + e] * H1 + h] + adv) - m);
    alphaE[(size_t)h * EP + base + e] = a;
    ss += a;
  }
  ss += __shfl_xor(ss, 8);
  ss += __shfl_xor(ss, 16);
  ss += __shfl_xor(ss, 32);
  if (et == 0) inv1[n * H1 + h] = 1.f / (ss + 1e-16f);
}

// ---------------- agg1 gather: head-sliced XCD-affine, unroll x4 pipelined ----------------
// bid&7 = head (round-robin block->XCD => per-XCD h1b re-read set = 2.56MB < 4MB L2).
// wave = 8 nodes x 1 head; 8 lanes/node x 16B. 4 independent row loads in flight per lane.
__global__ __launch_bounds__(256) void agg1_gather(const int* __restrict__ offsets,
                                                   const int* __restrict__ edge_src,
                                                   const float* __restrict__ alphaE,
                                                   const float* __restrict__ inv1,
                                                   const unsigned short* __restrict__ h1b,
                                                   const float* __restrict__ b1,
                                                   unsigned short* __restrict__ out1b) {
  int w = threadIdx.x >> 6, lane = threadIdx.x & 63;
  int bid = blockIdx.x;
  int head = bid & 7;
  int ng = bid >> 3;
  int sub = lane >> 3, cl = lane & 7;
  int n = ng * 32 + w * 8 + sub;
  int base = offsets[n];
  int deg = offsets[n + 1] - base;
  const float* aE = alphaE + (size_t)head * EP + base;
  const int* es = edge_src + base;
  const char* hb = (const char*)h1b + head * 128 + cl * 16;
  float acc[8] = {};
  int e = 0;
  for (; e + 3 < deg; e += 4) {
    float a0 = aE[e], a1 = aE[e + 1], a2 = aE[e + 2], a3 = aE[e + 3];
    int s0 = es[e], s1 = es[e + 1], s2 = es[e + 2], s3 = es[e + 3];
    uint4 u0 = *(const uint4*)(hb + ((size_t)s0 << 10));
    uint4 u1 = *(const uint4*)(hb + ((size_t)s1 << 10));
    uint4 u2 = *(const uint4*)(hb + ((size_t)s2 << 10));
    uint4 u3 = *(const uint4*)(hb + ((size_t)s3 << 10));
#pragma unroll
    for (int j = 0; j < 4; ++j) {
      unsigned int x0 = ((const unsigned int*)&u0)[j];
      unsigned int x1 = ((const unsigned int*)&u1)[j];
      unsigned int x2 = ((const unsigned int*)&u2)[j];
      unsigned int x3 = ((const unsigned int*)&u3)[j];
      acc[2 * j]     += a0 * asf(x0 << 16) + a1 * asf(x1 << 16)
                      + a2 * asf(x2 << 16) + a3 * asf(x3 << 16);
      acc[2 * j + 1] += a0 * asf(x0 & 0xffff0000u) + a1 * asf(x1 & 0xffff0000u)
                      + a2 * asf(x2 & 0xffff0000u) + a3 * asf(x3 & 0xffff0000u);
    }
  }
  for (; e < deg; ++e) {
    float a = aE[e];
    int s = es[e];
    uint4 uv = *(const uint4*)(hb + ((size_t)s << 10));
#pragma unroll
    for (int j = 0; j < 4; ++j) {
      unsigned int u = ((const unsigned int*)&uv)[j];
      acc[2 * j]     += a * asf(u << 16);
      acc[2 * j + 1] += a * asf(u & 0xffff0000u);
    }
  }
  float inv = inv1[n * H1 + head];
  int c0 = head * NHID + cl * 8;
  float4 b0 = *(const float4*)&b1[c0];
  float4 b4 = *(const float4*)&b1[c0 + 4];
  float v[8];
  v[0] = acc[0] * inv + b0.x; v[1] = acc[1] * inv + b0.y;
  v[2] = acc[2] * inv + b0.z; v[3] = acc[3] * inv + b0.w;
  v[4] = acc[4] * inv + b4.x; v[5] = acc[5] * inv + b4.y;
  v[6] = acc[6] * inv + b4.z; v[7] = acc[7] * inv + b4.w;
#pragma unroll
  for (int j = 0; j < 8; ++j) v[j] = v[j] > 0.f ? v[j] : (__expf(v[j]) - 1.f);  // ELU
  ushort4 o0 = make_ushort4(f2bf(v[0]), f2bf(v[1]), f2bf(v[2]), f2bf(v[3]));
  ushort4 o1 = make_ushort4(f2bf(v[4]), f2bf(v[5]), f2bf(v[6]), f2bf(v[7]));
  *(ushort4*)&out1b[(size_t)n * D1 + c0] = o0;
  *(ushort4*)&out1b[(size_t)n * D1 + c0 + 4] = o1;
}

// ---------------- GEMM2 (MFMA): h2(f32) = out1b @ W2 (+pad), fused alpha2 ----------------
__global__ __launch_bounds__(256) void gemm2_mfma(const unsigned short* __restrict__ ab,
                                                  const unsigned short* __restrict__ wb2t,
                                                  const float* __restrict__ a_src2,
                                                  const float* __restrict__ a_dst2,
                                                  float* __restrict__ h2,
                                                  float* __restrict__ asrc,
                                                  float* __restrict__ adst) {
  __shared__ unsigned short As[64 * 64];
  __shared__ unsigned short Bs[48 * 64];
  int tid = threadIdx.x;
  int w = tid >> 6, lane = tid & 63;
  int row0 = blockIdx.x * 64;
  int cl = lane & 15, hi = lane >> 4;
  f32x4 acc[3] = {};
  for (int k0 = 0; k0 < D1; k0 += 64) {
#pragma unroll
    for (int c = 0; c < 2; ++c) {
      int slot = c * 256 + tid;
      int r = slot >> 3;
      int q = (slot & 7) ^ (r & 7);
      gload16(ab + (size_t)(row0 + r) * D1 + k0 + q * 8, (char*)As + (c * 256 + w * 64) * 16);
    }
    {
      int r = tid >> 3;
      int q = (tid & 7) ^ (r & 7);
      gload16(wb2t + (size_t)r * D1 + k0 + q * 8, (char*)Bs + (w * 64) * 16);
      if (tid < 128) {
        int slot2 = 256 + tid;
        int r2 = slot2 >> 3;
        int q2 = (slot2 & 7) ^ (r2 & 7);
        gload16(wb2t + (size_t)r2 * D1 + k0 + q2 * 8, (char*)Bs + ((256 + w * 64)) * 16);
      }
    }
    __syncthreads();
#pragma unroll
    for (int kk = 0; kk < 2; ++kk) {
      int ra = w * 16 + cl;
      bf16x8 a = *(const bf16x8*)&As[ra * 64 + (((kk * 4 + hi) ^ (ra & 7)) << 3)];
#pragma unroll
      for (int n = 0; n < 3; ++n) {
        int rb = n * 16 + cl;
        bf16x8 b = *(const bf16x8*)&Bs[rb * 64 + (((kk * 4 + hi) ^ (rb & 7)) << 3)];
        acc[n] = __builtin_amdgcn_mfma_f32_16x16x32_bf16(a, b, acc[n], 0, 0, 0);
      }
    }
    __syncthreads();
  }
  float asv[3], adv[3];
#pragma unroll
  for (int n = 0; n < 3; ++n) {
    int c = n * 16 + cl;
    asv[n] = (c < NCLS) ? a_src2[c] : 0.f;
    adv[n] = (c < NCLS) ? a_dst2[c] : 0.f;
  }
#pragma unroll
  for (int r = 0; r < 4; ++r) {
    int grow = row0 + w * 16 + hi * 4 + r;
    float ps = acc[0][r] * asv[0] + acc[1][r] * asv[1] + acc[2][r] * asv[2];
    float pd = acc[0][r] * adv[0] + acc[1][r] * adv[1] + acc[2][r] * adv[2];
#pragma unroll
    for (int o = 8; o > 0; o >>= 1) { ps += __shfl_xor(ps, o); pd += __shfl_xor(pd, o); }
    if (grow < N_NODES) {
#pragma unroll
      for (int n = 0; n < 3; ++n) {
        int c = n * 16 + cl;
        if (c < NCLS) h2[(size_t)grow * NCLS + c] = acc[n][r];
      }
      if (cl == 0) { asrc[grow] = ps; adst[grow] = pd; }
    }
  }
}

// ---------------- agg2: LDS alpha + f32x2 gather (6 edges/iter) + b2 + log_softmax ----------------
__global__ __launch_bounds__(256) void agg2_kernel(const int* __restrict__ offsets,
                                                   const int* __restrict__ edge_src,
                                                   const float* __restrict__ asrc,
                                                   const float* __restrict__ adst,
                                                   const float* __restrict__ h2,
                                                   const float* __restrict__ b2,
                                                   float* __restrict__ out) {
  __shared__ float lalpha[4][MAXD + 8];
  __shared__ int   lsoff[4][MAXD + 8];
  int w = threadIdx.x >> 6;
  int lane = threadIdx.x & 63;
  int n = blockIdx.x * 4 + w;
  int base = offsets[n];
  int deg = offsets[n + 1] - base;
  int degc = min(deg, MAXD);
  int degp = ((degc + 5) / 6) * 6;   // pad to 6 (fits MAXD+8 arrays)

  float advv = adst[n];
  float m = -INFINITY;
  for (int e = lane; e < deg; e += 64) {
    int s = edge_src[base + e];
    float ev = lrelu(asrc[s] + advv);
    if (e < MAXD) { lsoff[w][e] = s * (NCLS * 4); lalpha[w][e] = ev; }
    m = fmaxf(m, ev);
  }
  m = wave_max(m);
  float ssum = 0.f;
  for (int e = lane; e < deg; e += 64) {
    float ev;
    if (e < MAXD) ev = lalpha[w][e];
    else { int s = edge_src[base + e]; ev = lrelu(asrc[s] + advv); }
    ssum += __expf(ev - m);
  }
  float inv = 1.f / (wave_sum(ssum) + 1e-16f);
  for (int e = lane; e < degc; e += 64) lalpha[w][e] = __expf(lalpha[w][e] - m) * inv;
  {
    int e = degc + lane;
    if (e < degp) { lalpha[w][e] = 0.f; lsoff[w][e] = 0; }
  }
  __builtin_amdgcn_wave_barrier();

  int esub = lane / 20;
  int cg = lane - esub * 20;
  bool act = esub < 3;
  float ax = 0.f, ay = 0.f;
  const char* hb = (const char*)h2 + cg * 8;
  for (int i = 0; i < degp; i += 6) {
    if (act) {
      int sA = i + esub, sB = i + 3 + esub;
      float aA = lalpha[w][sA], aB = lalpha[w][sB];
      int oA = lsoff[w][sA], oB = lsoff[w][sB];
      float2 hA = *(const float2*)(hb + oA);
      float2 hB = *(const float2*)(hb + oB);
      ax += aA * hA.x + aB * hB.x;
      ay += aA * hA.y + aB * hB.y;
    }
  }
  for (int e = MAXD + esub; e < deg; e += 3) {   // guard, never runs
    if (act) {
      int s = edge_src[base + e];
      float a = __expf(lrelu(asrc[s] + advv) - m) * inv;
      float2 hv = *(const float2*)(hb + (size_t)s * (NCLS * 4));
      ax += a * hv.x; ay += a * hv.y;
    }
  }
  float ax1 = __shfl(ax, lane + 20), ax2 = __shfl(ax, lane + 40);
  float ay1 = __shfl(ay, lane + 20), ay2 = __shfl(ay, lane + 40);
  float v0 = -INFINITY, v1 = -INFINITY;
  if (lane < 20) {
    v0 = ax + ax1 + ax2 + b2[2 * cg];
    v1 = ay + ay1 + ay2 + b2[2 * cg + 1];
  }
  float m2 = wave_max(fmaxf(v0, v1));
  float se = wave_sum(lane < 20 ? __expf(v0 - m2) + __expf(v1 - m2) : 0.f);
  if (lane < 20) {
    float ls = logf(se);
    *(float2*)&out[(size_t)n * NCLS + 2 * cg] = make_float2(v0 - m2 - ls, v1 - m2 - ls);
  }
}

extern "C" void kernel_launch(void* const* d_in, const int* in_sizes, int n_in,
                              void* d_out, int out_size, void* d_ws, size_t ws_size,
                              hipStream_t stream) {
  const float* x   = (const float*)d_in[0];
  const int*   ei  = (const int*)d_in[1];
  const float* W1  = (const float*)d_in[2];
  const float* as1 = (const float*)d_in[3];
  const float* ad1 = (const float*)d_in[4];
  const float* b1  = (const float*)d_in[5];
  const float* W2  = (const float*)d_in[6];
  const float* as2 = (const float*)d_in[7];
  const float* ad2 = (const float*)d_in[8];
  const float* b2  = (const float*)d_in[9];
  float* out = (float*)d_out;

  char* ws = (char*)d_ws;
  size_t off = 0;
  auto alloc = [&](size_t bytes) -> char* {
    char* p = ws + off;
    off += (bytes + 255) & ~(size_t)255;
    return p;
  };
  int* deg      = (int*)alloc((size_t)N_NODES * 4);
  int* cursor   = (int*)alloc((size_t)N_NODES * 4);
  int* offsets  = (int*)alloc((size_t)(N_NODES + 1) * 4);
  int* edge_src = (int*)alloc((size_t)EP * 4);
  unsigned short* xb    = (unsigned short*)alloc((size_t)MPAD * F_IN * 2);
  unsigned short* wb1t  = (unsigned short*)alloc((size_t)D1 * F_IN * 2);
  unsigned short* wb2t  = (unsigned short*)alloc((size_t)48 * D1 * 2);
  unsigned short* h1b   = (unsigned short*)alloc((size_t)N_NODES * D1 * 2);
  unsigned short* out1b = (unsigned short*)alloc((size_t)MPAD * D1 * 2);
  float* asrc1  = (float*)alloc((size_t)N_NODES * H1 * 4);
  float* adst1  = (float*)alloc((size_t)N_NODES * H1 * 4);
  float* alphaE = (float*)alloc((size_t)H1 * EP * 4);
  float* inv1   = (float*)alloc((size_t)N_NODES * H1 * 4);
  float* h2     = (float*)alloc((size_t)N_NODES * NCLS * 4);
  float* asrc2  = (float*)alloc((size_t)N_NODES * 4);
  float* adst2  = (float*)alloc((size_t)N_NODES * 4);

  prep_kernel<<<PB_PAD, 256, 0, stream>>>(x, W1, W2, xb, wb1t, wb2t, deg, cursor, out1b);
  count_deg<<<(EP + 255) / 256, 256, 0, stream>>>(ei, deg);
  scan_kernel<<<1, SCAN_T, 0, stream>>>(deg, offsets);
  scatter_edges<<<(EP + 255) / 256, 256, 0, stream>>>(ei, offsets, cursor, edge_src);

  gemm1_mfma<<<157 * 4, 256, 0, stream>>>(xb, wb1t, as1, ad1, h1b, asrc1, adst1);
  alpha1_kernel<<<N_NODES / 4, 256, 0, stream>>>(offsets, edge_src, asrc1, adst1, alphaE, inv1);
  agg1_gather<<<(N_NODES / 32) * 8, 256, 0, stream>>>(offsets, edge_src, alphaE, inv1, h1b, b1, out1b);

  gemm2_mfma<<<MPAD / 64, 256, 0, stream>>>(out1b, wb2t, as2, ad2, h2, asrc2, adst2);
  agg2_kernel<<<N_NODES / 4, 256, 0, stream>>>(offsets, edge_src, asrc2, adst2, h2, b2, out);
}